// Round 1
// baseline (64.973 us; speedup 1.0000x reference)
//
#include <hip/hip_runtime.h>
#include <math.h>

// Problem: P=2, S=2, C=64, F=64, B=64
//   scores[p,s,c,d] = sum_{f,f2} dbfc[p,s,c,f,d,f2]      (256 MB reduction — the whole cost)
//   weights = softmax(scores, axis=d)
//   v[b,ps,c,f1] = sum_f0 X[b,ps,c,f0] * wV[f1,f0]
//   out[c, b, ps*64+f1] = sum_d weights[ps,c,d] * v[b,ps,d,f1]

// ---------------------------------------------------------------------------
// Kernel A: one block per (p,s,c) slab (F*C*F = 262144 floats = 1 MB).
// Within an f-slab of 4096 floats laid out [d][f2], thread t's float4 (idx t)
// always has d = t>>4. Accumulate over the 64 f-slabs, reduce across the 16
// threads sharing each d via shfl, then do the row softmax in the epilogue.
// ---------------------------------------------------------------------------
__global__ __launch_bounds__(1024) void scores_softmax_kernel(
    const float* __restrict__ dbfc, float* __restrict__ weights)
{
    const int bid = blockIdx.x;          // (p*S+s)*C + c, 0..255
    const int t   = threadIdx.x;         // 0..1023
    const float4* slab = reinterpret_cast<const float4*>(dbfc) + (size_t)bid * (262144 / 4);

    float acc = 0.f;
#pragma unroll 8
    for (int f = 0; f < 64; ++f) {
        float4 v = slab[f * 1024 + t];
        acc += (v.x + v.y) + (v.z + v.w);
    }
    // reduce across the 16 lanes that share d = t>>4 (groups never cross waves)
#pragma unroll
    for (int m = 1; m < 16; m <<= 1)
        acc += __shfl_xor(acc, m, 64);

    __shared__ float sm[64];
    if ((t & 15) == 0) sm[t >> 4] = acc;
    __syncthreads();

    // softmax over the 64 scores of this row, done by wave 0
    if (t < 64) {
        float v = sm[t];
        float mx = v;
#pragma unroll
        for (int m = 32; m >= 1; m >>= 1) mx = fmaxf(mx, __shfl_xor(mx, m, 64));
        float e = expf(v - mx);
        float s = e;
#pragma unroll
        for (int m = 32; m >= 1; m >>= 1) s += __shfl_xor(s, m, 64);
        weights[bid * 64 + t] = e / s;
    }
}

// ---------------------------------------------------------------------------
// Kernel B: one block per (ps, b). LDS rows use stride 68 floats (272 B):
// 16-byte aligned for ds_read_b128, and both access patterns (broadcast rows
// spaced 4 apart; consecutive rows across 16 lanes) are bank-conflict-free.
// Thread t: tc = t>>4 owns c in {4tc..4tc+3}; tf = t&15 owns f1 in {tf+16*fi}.
// ---------------------------------------------------------------------------
__global__ __launch_bounds__(256) void attn_out_kernel(
    const float* __restrict__ X, const float* __restrict__ wV,
    const float* __restrict__ weights, float* __restrict__ out)
{
    const int blk = blockIdx.x;   // 0..255
    const int ps  = blk >> 6;     // 0..3
    const int b   = blk & 63;     // 0..63
    const int t   = threadIdx.x;  // 0..255
    const int tc  = t >> 4;       // 0..15
    const int tf  = t & 15;       // 0..15

    __shared__ float Xs [64][68];   // X[b, ps, c, f0]
    __shared__ float wVs[64][68];   // wV[f1][f0]
    __shared__ float Ws [64][68];   // weights[ps][c][d]
    __shared__ float VsT[64][68];   // v transposed: [f1][c]

    const float4* xsrc = reinterpret_cast<const float4*>(X + (size_t)b * 16384 + ps * 4096);
    const float4* wsrc = reinterpret_cast<const float4*>(wV);
    const float4* ssrc = reinterpret_cast<const float4*>(weights + ps * 4096);
#pragma unroll
    for (int idx = t; idx < 1024; idx += 256) {
        int r = idx >> 4, j = (idx & 15) * 4;
        *reinterpret_cast<float4*>(&Xs [r][j]) = xsrc[idx];
        *reinterpret_cast<float4*>(&wVs[r][j]) = wsrc[idx];
        *reinterpret_cast<float4*>(&Ws [r][j]) = ssrc[idx];
    }
    __syncthreads();

    // v: acc[ci][fi] = sum_f0 Xs[4tc+ci][f0] * wVs[tf+16fi][f0]
    float acc[4][4] = {};
    for (int f0 = 0; f0 < 64; f0 += 4) {
        float4 xa[4], wv[4];
#pragma unroll
        for (int ci = 0; ci < 4; ++ci)
            xa[ci] = *reinterpret_cast<const float4*>(&Xs[4 * tc + ci][f0]);
#pragma unroll
        for (int fi = 0; fi < 4; ++fi)
            wv[fi] = *reinterpret_cast<const float4*>(&wVs[tf + 16 * fi][f0]);
#pragma unroll
        for (int ci = 0; ci < 4; ++ci)
#pragma unroll
            for (int fi = 0; fi < 4; ++fi)
                acc[ci][fi] += xa[ci].x * wv[fi].x + xa[ci].y * wv[fi].y
                             + xa[ci].z * wv[fi].z + xa[ci].w * wv[fi].w;
    }
#pragma unroll
    for (int ci = 0; ci < 4; ++ci)
#pragma unroll
        for (int fi = 0; fi < 4; ++fi)
            VsT[tf + 16 * fi][4 * tc + ci] = acc[ci][fi];
    __syncthreads();

    // out: o[ci][fi] = sum_d Ws[4tc+ci][d] * VsT[tf+16fi][d]
    float o[4][4] = {};
    for (int d = 0; d < 64; d += 4) {
        float4 wa[4], va[4];
#pragma unroll
        for (int ci = 0; ci < 4; ++ci)
            wa[ci] = *reinterpret_cast<const float4*>(&Ws[4 * tc + ci][d]);
#pragma unroll
        for (int fi = 0; fi < 4; ++fi)
            va[fi] = *reinterpret_cast<const float4*>(&VsT[tf + 16 * fi][d]);
#pragma unroll
        for (int ci = 0; ci < 4; ++ci)
#pragma unroll
            for (int fi = 0; fi < 4; ++fi)
                o[ci][fi] += wa[ci].x * va[fi].x + wa[ci].y * va[fi].y
                           + wa[ci].z * va[fi].z + wa[ci].w * va[fi].w;
    }

    // out[c, b, ps*64 + f1],  c = 4tc+ci,  f1 = tf+16fi
#pragma unroll
    for (int ci = 0; ci < 4; ++ci) {
        const int c = 4 * tc + ci;
        float* orow = out + ((size_t)c * 64 + b) * 256 + ps * 64;
#pragma unroll
        for (int fi = 0; fi < 4; ++fi)
            orow[tf + 16 * fi] = o[ci][fi];
    }
}

extern "C" void kernel_launch(void* const* d_in, const int* in_sizes, int n_in,
                              void* d_out, int out_size, void* d_ws, size_t ws_size,
                              hipStream_t stream)
{
    const float* X    = (const float*)d_in[0];  // [64, 16384]
    const float* dbfc = (const float*)d_in[1];  // [2,2,64,64,64,64]
    const float* wV   = (const float*)d_in[2];  // [64, 64]
    float* out        = (float*)d_out;          // [64, 64, 256]
    float* weights    = (float*)d_ws;           // [4, 64, 64] = 64 KB scratch

    scores_softmax_kernel<<<256, 1024, 0, stream>>>(dbfc, weights);
    attn_out_kernel<<<256, 256, 0, stream>>>(X, wV, weights, out);
}

// Round 2
// 59.912 us; speedup vs baseline: 1.0845x; 1.0845x over previous
//
#include <hip/hip_runtime.h>
#include <math.h>

// Problem: P=2, S=2, C=64, F=64, B=64
//   scores[p,s,c,d] = sum_{f,f2} dbfc[p,s,c,f,d,f2]      (268 MB reduction — the whole cost)
//   weights = softmax(scores, axis=d)                     (fused into kernel B prologue)
//   v[b,ps,c,f1] = sum_f0 X[b,ps,c,f0] * wV[f1,f0]
//   out[c, b, ps*64+f1] = sum_d weights[ps,c,d] * v[b,ps,d,f1]

// ---------------------------------------------------------------------------
// Kernel A: 2048 blocks x 256 threads. Block = 1/8 of a (p,s,c) slab
// (128 KB contiguous = 8 f-values x [d=64][f2=64]). Within the chunk, the
// float4 at local index j has d = (j>>4)&63; thread t at iteration i has
// j = i*256+t  ->  d = (t>>4) + 16*(i&3), so 4 register accumulators per
// thread cover all its d's. 16-lane shfl reduce, then 64 atomicAdds/block
// into scores[] (zeroed by a memset node). 8 blocks/CU -> 32 waves/CU.
// ---------------------------------------------------------------------------
__global__ __launch_bounds__(256) void scores_partial_kernel(
    const float* __restrict__ dbfc, float* __restrict__ scores)
{
    const int bid   = blockIdx.x;         // 0..2047
    const int slab  = bid >> 3;           // (ps*64 + c)
    const int chunk = bid & 7;
    const int t     = threadIdx.x;        // 0..255

    const float4* src = reinterpret_cast<const float4*>(dbfc)
                      + (size_t)slab * 65536 + chunk * 8192 + t;

    float4 a0 = make_float4(0.f, 0.f, 0.f, 0.f), a1 = a0, a2 = a0, a3 = a0;
#pragma unroll 2
    for (int i = 0; i < 32; i += 4) {
        float4 v0 = src[(i + 0) * 256];
        float4 v1 = src[(i + 1) * 256];
        float4 v2 = src[(i + 2) * 256];
        float4 v3 = src[(i + 3) * 256];
        a0.x += v0.x; a0.y += v0.y; a0.z += v0.z; a0.w += v0.w;
        a1.x += v1.x; a1.y += v1.y; a1.z += v1.z; a1.w += v1.w;
        a2.x += v2.x; a2.y += v2.y; a2.z += v2.z; a2.w += v2.w;
        a3.x += v3.x; a3.y += v3.y; a3.z += v3.z; a3.w += v3.w;
    }
    float s0 = (a0.x + a0.y) + (a0.z + a0.w);
    float s1 = (a1.x + a1.y) + (a1.z + a1.w);
    float s2 = (a2.x + a2.y) + (a2.z + a2.w);
    float s3 = (a3.x + a3.y) + (a3.z + a3.w);
#pragma unroll
    for (int m = 1; m < 16; m <<= 1) {
        s0 += __shfl_xor(s0, m, 64);
        s1 += __shfl_xor(s1, m, 64);
        s2 += __shfl_xor(s2, m, 64);
        s3 += __shfl_xor(s3, m, 64);
    }
    if ((t & 15) == 0) {
        float* dst = scores + slab * 64 + (t >> 4);
        atomicAdd(dst +  0, s0);
        atomicAdd(dst + 16, s1);
        atomicAdd(dst + 32, s2);
        atomicAdd(dst + 48, s3);
    }
}

// ---------------------------------------------------------------------------
// Kernel B: one block per (ps, b). Stages X-slab / wV / raw scores in LDS
// (row stride 68 floats: 16B-aligned, conflict-free for both access shapes),
// does the 64 row-softmaxes in the prologue (4 threads per row), computes
// v with 4x4 register tiles, transposes via LDS, then weights @ v.
// ---------------------------------------------------------------------------
__global__ __launch_bounds__(256) void attn_out_kernel(
    const float* __restrict__ X, const float* __restrict__ wV,
    const float* __restrict__ scores, float* __restrict__ out)
{
    const int blk = blockIdx.x;   // 0..255
    const int ps  = blk >> 6;     // 0..3
    const int b   = blk & 63;     // 0..63
    const int t   = threadIdx.x;  // 0..255
    const int tc  = t >> 4;       // 0..15
    const int tf  = t & 15;       // 0..15

    __shared__ float Xs [64][68];   // X[b, ps, c, f0]
    __shared__ float wVs[64][68];   // wV[f1][f0]
    __shared__ float Ws [64][68];   // scores -> softmaxed weights, [c][d]
    __shared__ float VsT[64][68];   // v transposed: [f1][c]

    const float4* xsrc = reinterpret_cast<const float4*>(X + (size_t)b * 16384 + ps * 4096);
    const float4* wsrc = reinterpret_cast<const float4*>(wV);
    const float4* ssrc = reinterpret_cast<const float4*>(scores + ps * 4096);
#pragma unroll
    for (int idx = t; idx < 1024; idx += 256) {
        int r = idx >> 4, j = (idx & 15) * 4;
        *reinterpret_cast<float4*>(&Xs [r][j]) = xsrc[idx];
        *reinterpret_cast<float4*>(&wVs[r][j]) = wsrc[idx];
        *reinterpret_cast<float4*>(&Ws [r][j]) = ssrc[idx];
    }
    __syncthreads();

    // v: acc[ci][fi] = sum_f0 Xs[4tc+ci][f0] * wVs[tf+16fi][f0]
    float acc[4][4] = {};
    for (int f0 = 0; f0 < 64; f0 += 4) {
        float4 xa[4], wv[4];
#pragma unroll
        for (int ci = 0; ci < 4; ++ci)
            xa[ci] = *reinterpret_cast<const float4*>(&Xs[4 * tc + ci][f0]);
#pragma unroll
        for (int fi = 0; fi < 4; ++fi)
            wv[fi] = *reinterpret_cast<const float4*>(&wVs[tf + 16 * fi][f0]);
#pragma unroll
        for (int ci = 0; ci < 4; ++ci)
#pragma unroll
            for (int fi = 0; fi < 4; ++fi)
                acc[ci][fi] += xa[ci].x * wv[fi].x + xa[ci].y * wv[fi].y
                             + xa[ci].z * wv[fi].z + xa[ci].w * wv[fi].w;
    }

    // softmax over d for each of the 64 rows of Ws; 4 threads per row
    {
        const int row = t >> 2, q = (t & 3) * 16;
        float e[16];
        float mx = -INFINITY;
#pragma unroll
        for (int i = 0; i < 16; ++i) mx = fmaxf(mx, Ws[row][q + i]);
        mx = fmaxf(mx, __shfl_xor(mx, 1, 64));
        mx = fmaxf(mx, __shfl_xor(mx, 2, 64));
        float sum = 0.f;
#pragma unroll
        for (int i = 0; i < 16; ++i) { e[i] = expf(Ws[row][q + i] - mx); sum += e[i]; }
        sum += __shfl_xor(sum, 1, 64);
        sum += __shfl_xor(sum, 2, 64);
        const float rinv = 1.0f / sum;
#pragma unroll
        for (int i = 0; i < 16; ++i) Ws[row][q + i] = e[i] * rinv;
    }

    // v -> LDS transposed
#pragma unroll
    for (int ci = 0; ci < 4; ++ci)
#pragma unroll
        for (int fi = 0; fi < 4; ++fi)
            VsT[tf + 16 * fi][4 * tc + ci] = acc[ci][fi];
    __syncthreads();

    // out: o[ci][fi] = sum_d Ws[4tc+ci][d] * VsT[tf+16fi][d]
    float o[4][4] = {};
    for (int d = 0; d < 64; d += 4) {
        float4 wa[4], va[4];
#pragma unroll
        for (int ci = 0; ci < 4; ++ci)
            wa[ci] = *reinterpret_cast<const float4*>(&Ws[4 * tc + ci][d]);
#pragma unroll
        for (int fi = 0; fi < 4; ++fi)
            va[fi] = *reinterpret_cast<const float4*>(&VsT[tf + 16 * fi][d]);
#pragma unroll
        for (int ci = 0; ci < 4; ++ci)
#pragma unroll
            for (int fi = 0; fi < 4; ++fi)
                o[ci][fi] += wa[ci].x * va[fi].x + wa[ci].y * va[fi].y
                           + wa[ci].z * va[fi].z + wa[ci].w * va[fi].w;
    }

    // out[c, b, ps*64 + f1],  c = 4tc+ci,  f1 = tf+16fi
#pragma unroll
    for (int ci = 0; ci < 4; ++ci) {
        const int c = 4 * tc + ci;
        float* orow = out + ((size_t)c * 64 + b) * 256 + ps * 64;
#pragma unroll
        for (int fi = 0; fi < 4; ++fi)
            orow[tf + 16 * fi] = o[ci][fi];
    }
}

extern "C" void kernel_launch(void* const* d_in, const int* in_sizes, int n_in,
                              void* d_out, int out_size, void* d_ws, size_t ws_size,
                              hipStream_t stream)
{
    const float* X    = (const float*)d_in[0];  // [64, 16384]
    const float* dbfc = (const float*)d_in[1];  // [2,2,64,64,64,64]
    const float* wV   = (const float*)d_in[2];  // [64, 64]
    float* out        = (float*)d_out;          // [64, 64, 256]
    float* scores     = (float*)d_ws;           // [4, 64, 64] = 64 KB scratch

    hipMemsetAsync(scores, 0, 4 * 64 * 64 * sizeof(float), stream);
    scores_partial_kernel<<<2048, 256, 0, stream>>>(dbfc, scores);
    attn_out_kernel<<<256, 256, 0, stream>>>(X, wV, scores, out);
}

// Round 4
// 54.837 us; speedup vs baseline: 1.1848x; 1.0925x over previous
//
#include <hip/hip_runtime.h>
#include <math.h>

// Problem: P=2, S=2, C=64, F=64, B=64
//   scores[p,s,c,d] = sum_{f,f2} dbfc[p,s,c,f,d,f2]      (268 MB streaming reduction)
//   weights = softmax(scores, axis=d)                     (fused into kernel B prologue)
//   v[b,ps,c,f1] = sum_f0 X[b,ps,c,f0] * wV[f1,f0]
//   out[c, b, ps*64+f1] = sum_d weights[ps,c,d] * v[b,ps,d,f1]

// clang native vector type — __builtin_nontemporal_load requires this
// (HIP_vector_type float4 is a struct and is rejected).
typedef float floatx4 __attribute__((ext_vector_type(4)));

// ---------------------------------------------------------------------------
// Kernel A: 2048 blocks x 256 threads. Block = 1/8 of a (p,s,c) slab
// (128 KB contiguous = 8 f-values x [d=64][f2=64]). Thread t at iter i reads
// local float4 j = i*256+t -> d = (t>>4) + 16*(i&3): 4 register accumulators.
// Nontemporal loads (pure stream, zero reuse). 16-lane shfl reduce, then
// plain stores of this chunk's 64 partial sums (no atomics, no memset).
// ---------------------------------------------------------------------------
__global__ __launch_bounds__(256) void scores_partial_kernel(
    const float* __restrict__ dbfc, float* __restrict__ partials)
{
    const int bid   = blockIdx.x;         // 0..2047
    const int slab  = bid >> 3;           // (ps*64 + c)
    const int chunk = bid & 7;
    const int t     = threadIdx.x;        // 0..255

    const floatx4* src = reinterpret_cast<const floatx4*>(dbfc)
                       + (size_t)slab * 65536 + chunk * 8192 + t;

    floatx4 a0 = (floatx4)0.f, a1 = (floatx4)0.f, a2 = (floatx4)0.f, a3 = (floatx4)0.f;
#pragma unroll 2
    for (int i = 0; i < 32; i += 4) {
        floatx4 v0 = __builtin_nontemporal_load(&src[(i + 0) * 256]);
        floatx4 v1 = __builtin_nontemporal_load(&src[(i + 1) * 256]);
        floatx4 v2 = __builtin_nontemporal_load(&src[(i + 2) * 256]);
        floatx4 v3 = __builtin_nontemporal_load(&src[(i + 3) * 256]);
        a0 += v0;
        a1 += v1;
        a2 += v2;
        a3 += v3;
    }
    float s0 = (a0.x + a0.y) + (a0.z + a0.w);
    float s1 = (a1.x + a1.y) + (a1.z + a1.w);
    float s2 = (a2.x + a2.y) + (a2.z + a2.w);
    float s3 = (a3.x + a3.y) + (a3.z + a3.w);
#pragma unroll
    for (int m = 1; m < 16; m <<= 1) {
        s0 += __shfl_xor(s0, m, 64);
        s1 += __shfl_xor(s1, m, 64);
        s2 += __shfl_xor(s2, m, 64);
        s3 += __shfl_xor(s3, m, 64);
    }
    if ((t & 15) == 0) {
        float* dst = partials + (size_t)chunk * 16384 + slab * 64 + (t >> 4);
        dst[ 0] = s0;
        dst[16] = s1;
        dst[32] = s2;
        dst[48] = s3;
    }
}

// ---------------------------------------------------------------------------
// Kernel B: one block per (ps, b). Stages X-slab / wV in LDS, reduces the 8
// score partials into Ws while staging, softmaxes the 64 rows (4 thr/row),
// computes v with 4x4 register tiles, transposes via LDS, then weights @ v.
// LDS rows stride 68 floats: 16B-aligned, conflict-free for both patterns.
// ---------------------------------------------------------------------------
__global__ __launch_bounds__(256) void attn_out_kernel(
    const float* __restrict__ X, const float* __restrict__ wV,
    const float* __restrict__ partials, float* __restrict__ out)
{
    const int blk = blockIdx.x;   // 0..255
    const int ps  = blk >> 6;     // 0..3
    const int b   = blk & 63;     // 0..63
    const int t   = threadIdx.x;  // 0..255
    const int tc  = t >> 4;       // 0..15
    const int tf  = t & 15;       // 0..15

    __shared__ float Xs [64][68];   // X[b, ps, c, f0]
    __shared__ float wVs[64][68];   // wV[f1][f0]
    __shared__ float Ws [64][68];   // summed scores -> softmaxed weights [c][d]
    __shared__ float VsT[64][68];   // v transposed: [f1][c]

    const float4* xsrc = reinterpret_cast<const float4*>(X + (size_t)b * 16384 + ps * 4096);
    const float4* wsrc = reinterpret_cast<const float4*>(wV);
    const float4* psrc = reinterpret_cast<const float4*>(partials);
#pragma unroll
    for (int idx = t; idx < 1024; idx += 256) {
        int r = idx >> 4, jq = idx & 15, j = jq * 4;
        *reinterpret_cast<float4*>(&Xs [r][j]) = xsrc[idx];
        *reinterpret_cast<float4*>(&wVs[r][j]) = wsrc[idx];
        // sum the 8 chunk partials for (c=r, d=j..j+3)
        float4 s = make_float4(0.f, 0.f, 0.f, 0.f);
#pragma unroll
        for (int k = 0; k < 8; ++k) {
            float4 p = psrc[k * 4096 + (ps * 64 + r) * 16 + jq];
            s.x += p.x; s.y += p.y; s.z += p.z; s.w += p.w;
        }
        *reinterpret_cast<float4*>(&Ws [r][j]) = s;
    }
    __syncthreads();

    // v: acc[ci][fi] = sum_f0 Xs[4tc+ci][f0] * wVs[tf+16fi][f0]
    float acc[4][4] = {};
    for (int f0 = 0; f0 < 64; f0 += 4) {
        float4 xa[4], wv[4];
#pragma unroll
        for (int ci = 0; ci < 4; ++ci)
            xa[ci] = *reinterpret_cast<const float4*>(&Xs[4 * tc + ci][f0]);
#pragma unroll
        for (int fi = 0; fi < 4; ++fi)
            wv[fi] = *reinterpret_cast<const float4*>(&wVs[tf + 16 * fi][f0]);
#pragma unroll
        for (int ci = 0; ci < 4; ++ci)
#pragma unroll
            for (int fi = 0; fi < 4; ++fi)
                acc[ci][fi] += xa[ci].x * wv[fi].x + xa[ci].y * wv[fi].y
                             + xa[ci].z * wv[fi].z + xa[ci].w * wv[fi].w;
    }

    // softmax over d for each of the 64 rows of Ws; 4 threads per row
    {
        const int row = t >> 2, q = (t & 3) * 16;
        float e[16];
        float mx = -INFINITY;
#pragma unroll
        for (int i = 0; i < 16; ++i) mx = fmaxf(mx, Ws[row][q + i]);
        mx = fmaxf(mx, __shfl_xor(mx, 1, 64));
        mx = fmaxf(mx, __shfl_xor(mx, 2, 64));
        float sum = 0.f;
#pragma unroll
        for (int i = 0; i < 16; ++i) { e[i] = expf(Ws[row][q + i] - mx); sum += e[i]; }
        sum += __shfl_xor(sum, 1, 64);
        sum += __shfl_xor(sum, 2, 64);
        const float rinv = 1.0f / sum;
#pragma unroll
        for (int i = 0; i < 16; ++i) Ws[row][q + i] = e[i] * rinv;
    }

    // v -> LDS transposed
#pragma unroll
    for (int ci = 0; ci < 4; ++ci)
#pragma unroll
        for (int fi = 0; fi < 4; ++fi)
            VsT[tf + 16 * fi][4 * tc + ci] = acc[ci][fi];
    __syncthreads();

    // out: o[ci][fi] = sum_d Ws[4tc+ci][d] * VsT[tf+16fi][d]
    float o[4][4] = {};
    for (int d = 0; d < 64; d += 4) {
        float4 wa[4], va[4];
#pragma unroll
        for (int ci = 0; ci < 4; ++ci)
            wa[ci] = *reinterpret_cast<const float4*>(&Ws[4 * tc + ci][d]);
#pragma unroll
        for (int fi = 0; fi < 4; ++fi)
            va[fi] = *reinterpret_cast<const float4*>(&VsT[tf + 16 * fi][d]);
#pragma unroll
        for (int ci = 0; ci < 4; ++ci)
#pragma unroll
            for (int fi = 0; fi < 4; ++fi)
                o[ci][fi] += wa[ci].x * va[fi].x + wa[ci].y * va[fi].y
                           + wa[ci].z * va[fi].z + wa[ci].w * va[fi].w;
    }

    // out[c, b, ps*64 + f1],  c = 4tc+ci,  f1 = tf+16fi
#pragma unroll
    for (int ci = 0; ci < 4; ++ci) {
        const int c = 4 * tc + ci;
        float* orow = out + ((size_t)c * 64 + b) * 256 + ps * 64;
#pragma unroll
        for (int fi = 0; fi < 4; ++fi)
            orow[tf + 16 * fi] = o[ci][fi];
    }
}

extern "C" void kernel_launch(void* const* d_in, const int* in_sizes, int n_in,
                              void* d_out, int out_size, void* d_ws, size_t ws_size,
                              hipStream_t stream)
{
    const float* X    = (const float*)d_in[0];  // [64, 16384]
    const float* dbfc = (const float*)d_in[1];  // [2,2,64,64,64,64]
    const float* wV   = (const float*)d_in[2];  // [64, 64]
    float* out        = (float*)d_out;          // [64, 64, 256]
    float* partials   = (float*)d_ws;           // [8][256][64] = 512 KB scratch

    scores_partial_kernel<<<2048, 256, 0, stream>>>(dbfc, partials);
    attn_out_kernel<<<256, 256, 0, stream>>>(X, wV, partials, out);
}